// Round 4
// baseline (1127.379 us; speedup 1.0000x reference)
//
#include <hip/hip_runtime.h>
#include <hip/hip_bf16.h>
#include <math.h>

#define Bb 512
#define Ll 71
#define Dd 512
#define Hh 8
#define DH 64
#define MM (Bb*Ll)   // 36352 = 284 * 128

typedef __attribute__((ext_vector_type(8))) short short8;
typedef __attribute__((ext_vector_type(4))) float f32x4;

static __device__ __forceinline__ f32x4 mfma_bf16(short8 a, short8 b, f32x4 c) {
    return __builtin_amdgcn_mfma_f32_16x16x32_bf16(a, b, c, 0, 0, 0);
}

// fp32 -> bf16 with round-to-nearest-even
static __device__ __forceinline__ unsigned short f2bf(float f) {
    union { float f; unsigned u; } v; v.f = f;
    unsigned r = v.u + 0x7FFFu + ((v.u >> 16) & 1u);
    return (unsigned short)(r >> 16);
}

// ---------------------------------------------------------------------------
// Projection accumulate: acc[t] += X_rows @ W[:, hs + t*16 + l16 block]
// A: 8 contiguous fp32 from global, converted to bf16.
// B: 8 stride-512 fp32 gathered from row-major W [512 k][512 n], converted.
// ---------------------------------------------------------------------------
static __device__ __forceinline__ void proj_g(
    const float* __restrict__ Xrows,
    const float* __restrict__ W,
    int hs, int wave, int quad, int l16, f32x4 acc[4])
{
    const int arow = wave * 16 + l16;
    const bool ok = (arow < 71);
    const float* ap = Xrows + (size_t)arow * 512 + quad * 8;
    const int nb = hs + l16;
#pragma unroll 2
    for (int kk = 0; kk < 16; ++kk) {
        short8 a;
        if (ok) {
            const float* p = ap + (size_t)kk * 32;
#pragma unroll
            for (int j = 0; j < 8; j++) a[j] = (short)f2bf(p[j]);
        } else {
            a = (short8){0,0,0,0,0,0,0,0};
        }
        const int k0 = kk * 32 + quad * 8;
#pragma unroll
        for (int t = 0; t < 4; t++) {
            const float* wp = W + (size_t)k0 * 512 + nb + t * 16;
            short8 bw;
#pragma unroll
            for (int j = 0; j < 8; j++) bw[j] = (short)f2bf(wp[(size_t)j * 512]);
            acc[t] = mfma_bf16(a, bw, acc[t]);
        }
    }
}

// ---------------------------------------------------------------------------
// Kernel 1: fused QKV-projection + attention per (b,h). 320 threads = 5 waves.
// All global I/O is fp32. Writes attention output (fp32) into X2 = d_out.
// Zero bytes of d_ws used.
// ---------------------------------------------------------------------------
__global__ __launch_bounds__(320) void attn_fused(
    const float* __restrict__ query,
    const float* __restrict__ key_,
    const float* __restrict__ value,
    const float* __restrict__ Wq, const float* __restrict__ bq,
    const float* __restrict__ Wk, const float* __restrict__ bk,
    const float* __restrict__ Wv, const float* __restrict__ bv,
    const float* __restrict__ w1,  // [71][128] row-major
    const float* __restrict__ b1,  // [128]
    const float* __restrict__ w2,  // [128][71] row-major
    const float* __restrict__ b2,  // [71]
    float* __restrict__ X2)        // [36352][512] fp32
{
    __shared__ __align__(16) unsigned short smem[26496];
    unsigned short* Qs  = smem;              // [80][72] bf16
    unsigned short* Ks  = smem + 5760;       // [80][72] bf16
    unsigned short* H1s = smem;              // [80][136] overlays Qs+Ks
    unsigned short* VTs = smem + 11520;      // [64][104]  V^T, k-contig
    unsigned short* Sb  = smem + 18176;      // [80][104]

    const int tid = threadIdx.x;
    const int wave = tid >> 6, lane = tid & 63;
    const int quad = lane >> 4, l16 = lane & 15;
    const int bh = blockIdx.x, b = bh >> 3, h = bh & 7, hs = h * 64;
    const float* Xq = query + (size_t)(b * 71) * 512;
    const float* Xk = key_  + (size_t)(b * 71) * 512;
    const float* Xv = value + (size_t)(b * 71) * 512;

    // zero pads (MFMA 0*junk != 0 unless pads are real zeros)
    for (int i = tid; i < 1280; i += 320) {           // Sb cols [80,96)
        int r = i >> 4, c = 80 + (i & 15);
        Sb[r * 104 + c] = 0;
    }
    for (int i = tid; i < 1024; i += 320) {           // VTs k-cols [80,96)
        int n = i >> 4, c = 80 + (i & 15);
        VTs[n * 104 + c] = 0;
    }

    // ---- Q projection -> Qs[80][72]
    {
        f32x4 acc[4];
#pragma unroll
        for (int t = 0; t < 4; t++) acc[t] = (f32x4){0.f, 0.f, 0.f, 0.f};
        proj_g(Xq, Wq, hs, wave, quad, l16, acc);
#pragma unroll
        for (int t = 0; t < 4; t++) {
            int col = t * 16 + l16;
            float bb = bq[hs + col];
#pragma unroll
            for (int r = 0; r < 4; r++) {
                int row = wave * 16 + quad * 4 + r;
                Qs[row * 72 + col] = f2bf(acc[t][r] + bb);
            }
        }
    }
    // ---- K projection -> Ks[80][72]
    {
        f32x4 acc[4];
#pragma unroll
        for (int t = 0; t < 4; t++) acc[t] = (f32x4){0.f, 0.f, 0.f, 0.f};
        proj_g(Xk, Wk, hs, wave, quad, l16, acc);
#pragma unroll
        for (int t = 0; t < 4; t++) {
            int col = t * 16 + l16;
            float bb = bk[hs + col];
#pragma unroll
            for (int r = 0; r < 4; r++) {
                int row = wave * 16 + quad * 4 + r;
                Ks[row * 72 + col] = f2bf(acc[t][r] + bb);
            }
        }
    }
    // ---- V projection -> VTs[64][104] transposed; k-rows >=71 stored as 0
    {
        f32x4 acc[4];
#pragma unroll
        for (int t = 0; t < 4; t++) acc[t] = (f32x4){0.f, 0.f, 0.f, 0.f};
        proj_g(Xv, Wv, hs, wave, quad, l16, acc);
#pragma unroll
        for (int t = 0; t < 4; t++) {
            int col = t * 16 + l16;
            float bb = bv[hs + col];
#pragma unroll
            for (int r = 0; r < 4; r++) {
                int row = wave * 16 + quad * 4 + r;
                float v = (row < 71) ? (acc[t][r] + bb) : 0.f;
                VTs[col * 104 + row] = f2bf(v);
            }
        }
    }
    __syncthreads();

    // ---- phase 1: scores = Q K^T / 8   (C-layout regs kept live)
    f32x4 sacc[5];
#pragma unroll
    for (int t = 0; t < 5; t++) sacc[t] = (f32x4){0.f, 0.f, 0.f, 0.f};
#pragma unroll
    for (int kk = 0; kk < 2; kk++) {
        short8 aq = *(const short8*)&Qs[(wave * 16 + l16) * 72 + kk * 32 + quad * 8];
#pragma unroll
        for (int t = 0; t < 5; t++) {
            short8 bk_ = *(const short8*)&Ks[(t * 16 + l16) * 72 + kk * 32 + quad * 8];
            sacc[t] = mfma_bf16(aq, bk_, sacc[t]);
        }
    }
#pragma unroll
    for (int t = 0; t < 5; t++) {
#pragma unroll
        for (int r = 0; r < 4; r++) {
            sacc[t][r] *= 0.125f;
            int row = wave * 16 + quad * 4 + r, col = t * 16 + l16;
            Sb[row * 104 + col] = f2bf(sacc[t][r]);
        }
    }
    __syncthreads();

    // ---- phase 2: H1 = gelu(S @ W1 + b1); W1 gathered fp32, k>=71 -> 0
    f32x4 hacc[8];
#pragma unroll
    for (int t = 0; t < 8; t++) hacc[t] = (f32x4){0.f, 0.f, 0.f, 0.f};
#pragma unroll
    for (int kk = 0; kk < 3; kk++) {
        short8 a = *(const short8*)&Sb[(wave * 16 + l16) * 104 + kk * 32 + quad * 8];
        const int k0 = kk * 32 + quad * 8;
#pragma unroll
        for (int t = 0; t < 8; t++) {
            const float* wp = w1 + (size_t)k0 * 128 + t * 16 + l16;
            short8 bw;
#pragma unroll
            for (int j = 0; j < 8; j++)
                bw[j] = (k0 + j < 71) ? (short)f2bf(wp[(size_t)j * 128]) : (short)0;
            hacc[t] = mfma_bf16(a, bw, hacc[t]);
        }
    }
#pragma unroll
    for (int t = 0; t < 8; t++) {
        int col = t * 16 + l16;
        float bvf = b1[col];
#pragma unroll
        for (int r = 0; r < 4; r++) {
            float z = hacc[t][r] + bvf;
            float g = 0.5f * z * (1.0f + erff(z * 0.70710678118654752f));
            int row = wave * 16 + quad * 4 + r;
            H1s[row * 136 + col] = f2bf(g);
        }
    }
    __syncthreads();

    // ---- phase 3: G = H1 @ W2; W2 gathered fp32, out-cols >=71 -> 0
    f32x4 gacc[5];
#pragma unroll
    for (int t = 0; t < 5; t++) gacc[t] = (f32x4){0.f, 0.f, 0.f, 0.f};
#pragma unroll
    for (int kk = 0; kk < 4; kk++) {
        short8 a = *(const short8*)&H1s[(wave * 16 + l16) * 136 + kk * 32 + quad * 8];
        const int k0 = kk * 32 + quad * 8;
#pragma unroll
        for (int t = 0; t < 5; t++) {
            const int n = t * 16 + l16;
            const float* wp = w2 + (size_t)k0 * 71 + n;
            short8 bw;
#pragma unroll
            for (int j = 0; j < 8; j++)
                bw[j] = (n < 71) ? (short)f2bf(wp[(size_t)j * 71]) : (short)0;
            gacc[t] = mfma_bf16(a, bw, gacc[t]);
        }
    }
#pragma unroll
    for (int t = 0; t < 5; t++) {
        int col = t * 16 + l16;
        float b2v = (col < 71) ? b2[col] : 0.f;
#pragma unroll
        for (int r = 0; r < 4; r++)
            sacc[t][r] = sacc[t][r] + gacc[t][r] + b2v;
    }

    // ---- phase 4: softmax over cols 0..70 (row spread over 16 lanes x 5 regs)
    bool valid4 = (l16 < 7);
#pragma unroll
    for (int r = 0; r < 4; r++) {
        float mx = -1e30f;
#pragma unroll
        for (int t = 0; t < 5; t++) {
            float v = sacc[t][r];
            if (t == 4 && !valid4) v = -1e30f;
            mx = fmaxf(mx, v);
        }
#pragma unroll
        for (int off = 1; off < 16; off <<= 1) mx = fmaxf(mx, __shfl_xor(mx, off, 16));
        float sum = 0.f;
#pragma unroll
        for (int t = 0; t < 5; t++) {
            float e = (t == 4 && !valid4) ? 0.f : __expf(sacc[t][r] - mx);
            sacc[t][r] = e;
            sum += e;
        }
#pragma unroll
        for (int off = 1; off < 16; off <<= 1) sum += __shfl_xor(sum, off, 16);
        float inv = 1.0f / sum;
#pragma unroll
        for (int t = 0; t < 5; t++) sacc[t][r] *= inv;
    }
#pragma unroll
    for (int t = 0; t < 5; t++) {
#pragma unroll
        for (int r = 0; r < 4; r++) {
            int row = wave * 16 + quad * 4 + r, col = t * 16 + l16;
            Sb[row * 104 + col] = f2bf(sacc[t][r]);   // P; cols 71..95 exact 0
        }
    }
    __syncthreads();

    // ---- phase 5: O = P @ V ; store fp32 into X2
    f32x4 oacc[4];
#pragma unroll
    for (int t = 0; t < 4; t++) oacc[t] = (f32x4){0.f, 0.f, 0.f, 0.f};
#pragma unroll
    for (int kk = 0; kk < 3; kk++) {
        short8 a = *(const short8*)&Sb[(wave * 16 + l16) * 104 + kk * 32 + quad * 8];
#pragma unroll
        for (int t = 0; t < 4; t++) {
            short8 bvv = *(const short8*)&VTs[(t * 16 + l16) * 104 + kk * 32 + quad * 8];
            oacc[t] = mfma_bf16(a, bvv, oacc[t]);
        }
    }
#pragma unroll
    for (int r = 0; r < 4; r++) {
        int l = wave * 16 + quad * 4 + r;
        if (l < 71) {
#pragma unroll
            for (int t = 0; t < 4; t++) {
                int col = hs + t * 16 + l16;
                X2[(size_t)(b * 71 + l) * 512 + col] = oacc[t][r];
            }
        }
    }
}

// ---------------------------------------------------------------------------
// Kernel 2: IN-PLACE output projection on d_out (fp32). Block = 128-row
// stripe (8 waves, 64x128 per wave). Reads own rows as A from global,
// gathers Wo as B, barrier, overwrites own rows. No cross-block sharing.
// ---------------------------------------------------------------------------
__global__ __launch_bounds__(512, 2) void gemm_o_inplace(
    const float* __restrict__ Wo,   // [512 k][512 n] row-major fp32
    const float* __restrict__ bo,   // [512] fp32
    float* __restrict__ Y)          // [36352][512] fp32, in/out
{
    const int tid  = threadIdx.x;
    const int wave = tid >> 6, lane = tid & 63;
    const int quad = lane >> 4, l16 = lane & 15;
    const int m0 = blockIdx.x * 128;
    const int wm = (wave >> 2) * 64, wn = (wave & 3) * 128;

    f32x4 acc[4][8];
#pragma unroll
    for (int i = 0; i < 4; i++)
#pragma unroll
        for (int j = 0; j < 8; j++) acc[i][j] = (f32x4){0.f, 0.f, 0.f, 0.f};

    for (int kk = 0; kk < 16; ++kk) {
        const int k0 = kk * 32 + quad * 8;
        short8 af[4];
#pragma unroll
        for (int i = 0; i < 4; i++) {
            const float* p = Y + (size_t)(m0 + wm + i * 16 + l16) * 512 + k0;
            short8 a;
#pragma unroll
            for (int j = 0; j < 8; j++) a[j] = (short)f2bf(p[j]);
            af[i] = a;
        }
        short8 bfr[8];
#pragma unroll
        for (int j = 0; j < 8; j++) {
            const float* wp = Wo + (size_t)k0 * 512 + wn + j * 16 + l16;
            short8 bw;
#pragma unroll
            for (int e = 0; e < 8; e++) bw[e] = (short)f2bf(wp[(size_t)e * 512]);
            bfr[j] = bw;
        }
#pragma unroll
        for (int i = 0; i < 4; i++)
#pragma unroll
            for (int j = 0; j < 8; j++)
                acc[i][j] = mfma_bf16(af[i], bfr[j], acc[i][j]);
    }

    __syncthreads();   // all A-reads in this block complete before any write

#pragma unroll
    for (int j = 0; j < 8; j++) {
        int gcol = wn + j * 16 + l16;
        float bvf = bo[gcol];
#pragma unroll
        for (int i = 0; i < 4; i++) {
#pragma unroll
            for (int r = 0; r < 4; r++) {
                int grow = m0 + wm + i * 16 + quad * 4 + r;
                Y[(size_t)grow * 512 + gcol] = acc[i][j][r] + bvf;
            }
        }
    }
}

extern "C" void kernel_launch(void* const* d_in, const int* in_sizes, int n_in,
                              void* d_out, int out_size, void* d_ws, size_t ws_size,
                              hipStream_t stream) {
    (void)in_sizes; (void)n_in; (void)out_size; (void)d_ws; (void)ws_size;
    const float* query = (const float*)d_in[0];
    const float* key_  = (const float*)d_in[1];
    const float* value = (const float*)d_in[2];
    const float* Wq = (const float*)d_in[3];
    const float* bq = (const float*)d_in[4];
    const float* Wk = (const float*)d_in[5];
    const float* bk = (const float*)d_in[6];
    const float* Wv = (const float*)d_in[7];
    const float* bv = (const float*)d_in[8];
    const float* Wo = (const float*)d_in[9];
    const float* bo = (const float*)d_in[10];
    const float* w1 = (const float*)d_in[11];
    const float* b1 = (const float*)d_in[12];
    const float* w2 = (const float*)d_in[13];
    const float* b2 = (const float*)d_in[14];

    float* X2 = (float*)d_out;  // scratch, fully overwritten every call

    attn_fused<<<4096, 320, 0, stream>>>(query, key_, value,
                                         Wq, bq, Wk, bk, Wv, bv,
                                         w1, b1, w2, b2, X2);
    gemm_o_inplace<<<284, 512, 0, stream>>>(Wo, bo, X2);
}